// Round 4
// baseline (43280.222 us; speedup 1.0000x reference)
//
#include <hip/hip_runtime.h>
#include <hip/hip_fp16.h>

// LSTM (S=16384, I=64, H=1024) -> ReLU -> FC(1024->128) -> ReLU -> FC(128->1), last step only.
// Persistent kernel, W_hh register-resident across 64 blocks.
// Per-step device-wide h broadcast via self-validating 4-byte (tag16, fp16) pairs,
// relaxed agent-scope atomics (poll IS the data read, no fences).
// R4: single-poller-wave topology — only wave 15 of each block touches the fabric
// for polling (8x8-B coalesced words per lane), 15/16 waves stay quiet so producer
// stores land uncontended. Poller fans out to LDS with conflict-free float2 writes.

#define S_LEN 16384
#define I_DIM 64
#define H_DIM 1024
#define NBLK  64
#define NTHR  1024

__device__ __forceinline__ float sigmoidf_(float x) { return 1.0f / (1.0f + __expf(-x)); }
__device__ __forceinline__ float tanh_fast(float x) { return 1.0f - 2.0f / (__expf(2.0f * x) + 1.0f); }

// Block b owns h-indices 16b..16b+15 (64 gate rows). Wave w (0..15): gate g=w>>2,
// rows r0=(w&3)*4..+3. Lane c covers h-cols {s*256 + 4c .. +3}, s=0..3 (float4 LDS
// reads, 0 bank conflicts verified R1-R3), plus x-col c.
__global__ __launch_bounds__(NTHR, 4) void lstm_persistent(
    const float* __restrict__ xseq,   // [S, 64]
    const float* __restrict__ W_ih,   // [4096, 64]
    const float* __restrict__ W_hh,   // [4096, 1024]
    const float* __restrict__ b_ih,   // [4096]
    const float* __restrict__ b_hh,   // [4096]
    unsigned* __restrict__ pairs)     // [2][1024] 4-B pairs (tag16<<16 | fp16 bits)
{
    const int b   = blockIdx.x;
    const int tid = threadIdx.x;
    const int w   = tid >> 6;        // wave id 0..15
    const int c   = tid & 63;        // lane id
    const int g   = w >> 2;          // gate id (i,f,g,o)
    const int r0  = (w & 3) * 4;     // first of this wave's 4 rows (within 16)

    __shared__ float4 h_stage[H_DIM / 4];
    __shared__ float  x_stage[2][I_DIM];
    __shared__ float  gs[64];        // gate sums, index = gate*16 + row
    __shared__ float  bias_s[64];

    // ---- one-time: weights into registers (coalesced float4 loads) ----
    float4 wh[4][4];
    float  wi[4];
    #pragma unroll
    for (int q = 0; q < 4; ++q) {
        const int grow = g * H_DIM + 16 * b + r0 + q;
        const float4* wr = (const float4*)(W_hh + (size_t)grow * H_DIM);
        #pragma unroll
        for (int s = 0; s < 4; ++s) wh[q][s] = wr[s * 64 + c];
        wi[q] = W_ih[(size_t)grow * I_DIM + c];
    }
    if (tid < 64) {
        const int grow = (tid >> 4) * H_DIM + 16 * b + (tid & 15);
        bias_s[tid] = b_ih[grow] + b_hh[grow];
    }
    float cst = 0.0f;   // cell state in registers of threads tid<16
    if (tid < H_DIM / 4) h_stage[tid] = make_float4(0.f, 0.f, 0.f, 0.f);  // h_{-1}=0
    if (tid < 16) ((float4*)x_stage[0])[tid] = ((const float4*)xseq)[tid];
    __syncthreads();

    for (int t = 0; t < S_LEN; ++t) {
        // x prefetch for t+1 by wave 14 (off the producer/poller critical paths)
        if (w == 14 && c < 16 && t + 1 < S_LEN)
            ((float4*)x_stage[(t + 1) & 1])[c] =
                ((const float4*)(xseq + (size_t)(t + 1) * I_DIM))[c];

        // ---- gate dot products: W_hh . h_{t-1} + W_ih . x_t ----
        float acc[4] = {0.f, 0.f, 0.f, 0.f};
        #pragma unroll
        for (int s = 0; s < 4; ++s) {
            const float4 hv = h_stage[s * 64 + c];
            #pragma unroll
            for (int q = 0; q < 4; ++q) {
                acc[q] = fmaf(wh[q][s].x, hv.x, acc[q]);
                acc[q] = fmaf(wh[q][s].y, hv.y, acc[q]);
                acc[q] = fmaf(wh[q][s].z, hv.z, acc[q]);
                acc[q] = fmaf(wh[q][s].w, hv.w, acc[q]);
            }
        }
        {
            const float xv = x_stage[t & 1][c];
            #pragma unroll
            for (int q = 0; q < 4; ++q) acc[q] = fmaf(wi[q], xv, acc[q]);
        }
        // full-wave butterfly reduction
        #pragma unroll
        for (int q = 0; q < 4; ++q) {
            #pragma unroll
            for (int off = 32; off > 0; off >>= 1)
                acc[q] += __shfl_xor(acc[q], off, 64);
        }
        if (c == 0) {
            #pragma unroll
            for (int q = 0; q < 4; ++q) gs[g * 16 + r0 + q] = acc[q];
        }
        __syncthreads();

        // ---- activations + state update + publish (16 threads, 1 h-idx each) ----
        if (tid < 16) {
            const float pi  = gs[tid]      + bias_s[tid];
            const float pfg = gs[16 + tid] + bias_s[16 + tid];
            const float pg  = gs[32 + tid] + bias_s[32 + tid];
            const float po  = gs[48 + tid] + bias_s[48 + tid];
            const float ig = sigmoidf_(pi);
            const float fg = sigmoidf_(pfg);
            const float gg = tanh_fast(pg);
            const float og = sigmoidf_(po);
            cst = fg * cst + ig * gg;
            const float h = og * tanh_fast(cst);
            const unsigned pk = ((unsigned)(t + 1) << 16) |
                                (unsigned)__half_as_ushort(__float2half(h));
            // one 64-B line per block: 16 contiguous 4-B stores from lanes 0..15
            __hip_atomic_store(&pairs[(size_t)(t & 1) * H_DIM + 16 * b + tid], pk,
                               __ATOMIC_RELAXED, __HIP_MEMORY_SCOPE_AGENT);
        }

        if (t == S_LEN - 1) break;   // last h published; nothing left to read

        // ---- single-poller wave: lane c polls 8x8-B words (pairs 128u+2c, +1) ----
        if (w == 15) {
            const unsigned long long* P =
                (const unsigned long long*)(pairs + (size_t)(t & 1) * H_DIM);
            const unsigned long long tag = (unsigned long long)(unsigned)(t + 1);
            const unsigned long long expv = (tag << 48) | (tag << 16);
            const unsigned long long msk  = 0xFFFF0000FFFF0000ull;
            unsigned long long v[8];
            for (;;) {
                bool ok = true;
                #pragma unroll
                for (int u = 0; u < 8; ++u) {
                    v[u] = __hip_atomic_load(P + 64 * u + c,
                                             __ATOMIC_RELAXED, __HIP_MEMORY_SCOPE_AGENT);
                    ok = ok && ((v[u] & msk) == expv);
                }
                if (ok) break;
            }
            // fan out to LDS: float2 per lane, stride-1 across lanes -> 2-way = free
            float2* hs2 = (float2*)h_stage;
            #pragma unroll
            for (int u = 0; u < 8; ++u) {
                const float lo = __half2float(__ushort_as_half((unsigned short)(v[u] & 0xFFFFu)));
                const float hi = __half2float(__ushort_as_half((unsigned short)((v[u] >> 32) & 0xFFFFu)));
                hs2[64 * u + c] = make_float2(lo, hi);
            }
        }
        __syncthreads();
    }
}

// Final head: out = fc2( relu( fc1( relu(h_{S-1}) ) ) ). h_{S-1} is in pairs
// slot 1 ((S-1)&1). Kernel-boundary acquire makes plain loads safe.
__global__ __launch_bounds__(256) void fc_head(
    const unsigned* __restrict__ pairs,
    const float* __restrict__ fc1_w,  // [128, 1024]
    const float* __restrict__ fc1_b,  // [128]
    const float* __restrict__ fc2_w,  // [128]
    const float* __restrict__ fc2_b,  // [1]
    float* __restrict__ out)
{
    const int tid = threadIdx.x;
    __shared__ float4 hr4[H_DIM / 4];
    __shared__ float  partial[256];
    __shared__ float  r1[128];

    // extract fp16 h values from slot-1 pairs (4 pairs per thread)
    const uint4 pa = ((const uint4*)(pairs + H_DIM))[tid];
    float4 hv = make_float4(__half2float(__ushort_as_half((unsigned short)(pa.x & 0xFFFFu))),
                            __half2float(__ushort_as_half((unsigned short)(pa.y & 0xFFFFu))),
                            __half2float(__ushort_as_half((unsigned short)(pa.z & 0xFFFFu))),
                            __half2float(__ushort_as_half((unsigned short)(pa.w & 0xFFFFu))));
    hv.x = fmaxf(hv.x, 0.f); hv.y = fmaxf(hv.y, 0.f);
    hv.z = fmaxf(hv.z, 0.f); hv.w = fmaxf(hv.w, 0.f);
    hr4[tid] = hv;
    __syncthreads();

    const int row = tid & 127, half = tid >> 7;
    const float4* wrow = (const float4*)(fc1_w + (size_t)row * H_DIM) + half * 128;
    float a0 = 0.f, a1 = 0.f;
    #pragma unroll 4
    for (int i = 0; i < 128; i += 2) {
        const float4 w0 = wrow[i],     h0 = hr4[half * 128 + i];
        const float4 w1 = wrow[i + 1], h1 = hr4[half * 128 + i + 1];
        a0 += w0.x * h0.x + w0.y * h0.y + w0.z * h0.z + w0.w * h0.w;
        a1 += w1.x * h1.x + w1.y * h1.y + w1.z * h1.z + w1.w * h1.w;
    }
    partial[tid] = a0 + a1;
    __syncthreads();
    if (tid < 128) {
        const float s = partial[tid] + partial[tid + 128] + fc1_b[tid];
        r1[tid] = fmaxf(s, 0.f);
    }
    __syncthreads();
    if (tid < 64) {
        float v = r1[tid] * fc2_w[tid] + r1[tid + 64] * fc2_w[tid + 64];
        #pragma unroll
        for (int off = 32; off > 0; off >>= 1) v += __shfl_xor(v, off, 64);
        if (tid == 0) out[0] = v + fc2_b[0];
    }
}

extern "C" void kernel_launch(void* const* d_in, const int* in_sizes, int n_in,
                              void* d_out, int out_size, void* d_ws, size_t ws_size,
                              hipStream_t stream) {
    (void)in_sizes; (void)n_in; (void)out_size; (void)ws_size;
    const float* xseq  = (const float*)d_in[0];
    const float* W_ih  = (const float*)d_in[1];
    const float* W_hh  = (const float*)d_in[2];
    const float* b_ih  = (const float*)d_in[3];
    const float* b_hh  = (const float*)d_in[4];
    const float* fc1_w = (const float*)d_in[5];
    const float* fc1_b = (const float*)d_in[6];
    const float* fc2_w = (const float*)d_in[7];
    const float* fc2_b = (const float*)d_in[8];
    unsigned* pairs = (unsigned*)d_ws;

    lstm_persistent<<<NBLK, NTHR, 0, stream>>>(xseq, W_ih, W_hh, b_ih, b_hh, pairs);
    fc_head<<<1, 256, 0, stream>>>(pairs, fc1_w, fc1_b, fc2_w, fc2_b, (float*)d_out);
}

// Round 5
// 41111.554 us; speedup vs baseline: 1.0528x; 1.0528x over previous
//
#include <hip/hip_runtime.h>
#include <hip/hip_fp16.h>

// LSTM (S=16384, I=64, H=1024) -> ReLU -> FC(1024->128) -> ReLU -> FC(128->1), last step only.
// R5: TRUE register residency for W_hh. R1-R4 postmortem: VGPR_Count 52-68 proved the
// compiler rematerialized weight loads every step (256 KB/block/step streamed from L2,
// ~1+ us/step hidden cost). Fix: 512-thr blocks with __launch_bounds__(512,2) (256-VGPR
// cap), weights packed fp16 (64 VGPRs/lane), pinned with an opaque asm redefinition.
// Dot products via v_dot2_f32_f16 (fp32 accumulate). Sync: R2 pairs protocol (best
// measured): self-validating 4-B (tag16|fp16) pairs, relaxed agent atomics.

#define S_LEN 16384
#define I_DIM 64
#define H_DIM 1024
#define NBLK  64
#define NTHR  512

typedef _Float16 half2_t __attribute__((ext_vector_type(2)));

__device__ __forceinline__ float sigmoidf_(float x) { return 1.0f / (1.0f + __expf(-x)); }
__device__ __forceinline__ float tanh_fast(float x) { return 1.0f - 2.0f / (__expf(2.0f * x) + 1.0f); }
__device__ __forceinline__ unsigned pack2(float a, float b) {
    return (unsigned)__half_as_ushort(__float2half(a)) |
           ((unsigned)__half_as_ushort(__float2half(b)) << 16);
}

// Block b owns h-indices 16b..16b+15 (64 gate rows r=g*16+j). Wave w (0..7) handles
// rows rr=8w..8w+7. Lane c covers h-cols {s*256+4c..+3}, s=0..3 (8-B LDS reads,
// 2-way bank aliasing = free), packed as 8 half2 dwords per row = 64 weight VGPRs.
__global__ __launch_bounds__(NTHR, 2) void lstm_persistent(
    const float* __restrict__ xseq,   // [S, 64]
    const float* __restrict__ W_ih,   // [4096, 64]
    const float* __restrict__ W_hh,   // [4096, 1024]
    const float* __restrict__ b_ih,   // [4096]
    const float* __restrict__ b_hh,   // [4096]
    unsigned* __restrict__ pairs)     // [2][1024] 4-B pairs (tag16<<16 | fp16 bits)
{
    const int b   = blockIdx.x;
    const int tid = threadIdx.x;
    const int w   = tid >> 6;        // wave id 0..7
    const int c   = tid & 63;        // lane id

    __shared__ unsigned h_stage[H_DIM / 2];   // packed half2: dword i = h[2i],h[2i+1]
    __shared__ float    x_stage[2][I_DIM];
    __shared__ float    gs[64];               // gate sums, r = g*16 + j
    __shared__ float    bias_s[64];

    // ---- one-time: W_hh slice -> fp16 pairs in registers (coalesced float4 loads) ----
    unsigned wreg[8][8];   // [row][k], k=2s+{0,1} covers cols 256s+4c..+3
    float    wi[8];
    #pragma unroll
    for (int r = 0; r < 8; ++r) {
        const int rr   = 8 * w + r;
        const int grow = (rr >> 4) * H_DIM + 16 * b + (rr & 15);
        const float4* base = (const float4*)(W_hh + (size_t)grow * H_DIM);
        #pragma unroll
        for (int s = 0; s < 4; ++s) {
            const float4 f = base[s * 64 + c];
            wreg[r][2 * s]     = pack2(f.x, f.y);
            wreg[r][2 * s + 1] = pack2(f.z, f.w);
        }
        wi[r] = W_ih[(size_t)grow * I_DIM + c];
    }
    // opaque redefinition: compiler cannot rematerialize these inside the loop
    #pragma unroll
    for (int r = 0; r < 8; ++r)
        asm volatile("" : "+v"(wreg[r][0]), "+v"(wreg[r][1]), "+v"(wreg[r][2]),
                          "+v"(wreg[r][3]), "+v"(wreg[r][4]), "+v"(wreg[r][5]),
                          "+v"(wreg[r][6]), "+v"(wreg[r][7]));

    if (tid < 64) {
        const int grow = (tid >> 4) * H_DIM + 16 * b + (tid & 15);
        bias_s[tid] = b_ih[grow] + b_hh[grow];
    }
    float cst = 0.0f;                       // cell state in registers of threads tid<16
    h_stage[tid] = 0u;                      // h_{-1} = 0 (512 dwords)
    if (tid < 16) ((float4*)x_stage[0])[tid] = ((const float4*)xseq)[tid];
    __syncthreads();

    for (int t = 0; t < S_LEN; ++t) {
        // x prefetch for t+1 by wave 7 (off producer critical path)
        if (w == 7 && c < 16 && t + 1 < S_LEN)
            ((float4*)x_stage[(t + 1) & 1])[c] =
                ((const float4*)(xseq + (size_t)(t + 1) * I_DIM))[c];

        // ---- gate dots: W_hh . h_{t-1} (fp16 dot2) + W_ih . x_t (fp32) ----
        float acc[8] = {0.f, 0.f, 0.f, 0.f, 0.f, 0.f, 0.f, 0.f};
        #pragma unroll
        for (int s = 0; s < 4; ++s) {
            const uint2 hv = *(const uint2*)&h_stage[s * 128 + 2 * c];  // ds_read_b64
            const half2_t ha = __builtin_bit_cast(half2_t, hv.x);
            const half2_t hb = __builtin_bit_cast(half2_t, hv.y);
            #pragma unroll
            for (int r = 0; r < 8; ++r) {
                acc[r] = __builtin_amdgcn_fdot2(__builtin_bit_cast(half2_t, wreg[r][2 * s]),     ha, acc[r], false);
                acc[r] = __builtin_amdgcn_fdot2(__builtin_bit_cast(half2_t, wreg[r][2 * s + 1]), hb, acc[r], false);
            }
        }
        {
            const float xv = x_stage[t & 1][c];
            #pragma unroll
            for (int r = 0; r < 8; ++r) acc[r] = fmaf(wi[r], xv, acc[r]);
        }
        // full-wave butterfly reduction
        #pragma unroll
        for (int r = 0; r < 8; ++r) {
            #pragma unroll
            for (int off = 32; off > 0; off >>= 1)
                acc[r] += __shfl_xor(acc[r], off, 64);
        }
        if (c == 0) {
            #pragma unroll
            for (int r = 0; r < 8; ++r) gs[8 * w + r] = acc[r];
        }
        __syncthreads();

        // ---- activations + state update + publish (16 threads, 1 h-idx each) ----
        if (tid < 16) {
            const float pi  = gs[tid]      + bias_s[tid];
            const float pfg = gs[16 + tid] + bias_s[16 + tid];
            const float pg  = gs[32 + tid] + bias_s[32 + tid];
            const float po  = gs[48 + tid] + bias_s[48 + tid];
            const float ig = sigmoidf_(pi);
            const float fg = sigmoidf_(pfg);
            const float gg = tanh_fast(pg);
            const float og = sigmoidf_(po);
            cst = fg * cst + ig * gg;
            const float h = og * tanh_fast(cst);
            const unsigned pk = ((unsigned)(t + 1) << 16) |
                                (unsigned)__half_as_ushort(__float2half(h));
            // one 64-B line per block: 16 contiguous 4-B stores
            __hip_atomic_store(&pairs[(size_t)(t & 1) * H_DIM + 16 * b + tid], pk,
                               __ATOMIC_RELAXED, __HIP_MEMORY_SCOPE_AGENT);
        }

        if (t == S_LEN - 1) break;   // last h published; nothing left to read

        // ---- poll: thread tid waits on one 8-B word = pairs {2tid, 2tid+1} ----
        {
            const unsigned long long* P =
                (const unsigned long long*)(pairs + (size_t)(t & 1) * H_DIM);
            const unsigned long long tag  = (unsigned long long)(unsigned)(t + 1);
            const unsigned long long expv = (tag << 48) | (tag << 16);
            unsigned long long v;
            for (;;) {
                v = __hip_atomic_load(P + tid, __ATOMIC_RELAXED, __HIP_MEMORY_SCOPE_AGENT);
                if ((v & 0xFFFF0000FFFF0000ull) == expv) break;
                __builtin_amdgcn_s_sleep(1);
            }
            // pack the two fp16 payloads into one half2 dword (coalesced, conflict-free)
            h_stage[tid] = (unsigned)(v & 0xFFFFu) | (((unsigned)(v >> 32) & 0xFFFFu) << 16);
        }
        __syncthreads();
    }
}

// Final head: out = fc2( relu( fc1( relu(h_{S-1}) ) ) ). h_{S-1} is in pairs slot 1
// ((S-1)&1). Kernel-boundary ordering makes plain loads safe.
__global__ __launch_bounds__(256) void fc_head(
    const unsigned* __restrict__ pairs,
    const float* __restrict__ fc1_w,  // [128, 1024]
    const float* __restrict__ fc1_b,  // [128]
    const float* __restrict__ fc2_w,  // [128]
    const float* __restrict__ fc2_b,  // [1]
    float* __restrict__ out)
{
    const int tid = threadIdx.x;
    __shared__ float4 hr4[H_DIM / 4];
    __shared__ float  partial[256];
    __shared__ float  r1[128];

    // extract fp16 h values from slot-1 pairs (4 pairs per thread)
    const uint4 pa = ((const uint4*)(pairs + H_DIM))[tid];
    float4 hv = make_float4(__half2float(__ushort_as_half((unsigned short)(pa.x & 0xFFFFu))),
                            __half2float(__ushort_as_half((unsigned short)(pa.y & 0xFFFFu))),
                            __half2float(__ushort_as_half((unsigned short)(pa.z & 0xFFFFu))),
                            __half2float(__ushort_as_half((unsigned short)(pa.w & 0xFFFFu))));
    hv.x = fmaxf(hv.x, 0.f); hv.y = fmaxf(hv.y, 0.f);
    hv.z = fmaxf(hv.z, 0.f); hv.w = fmaxf(hv.w, 0.f);
    hr4[tid] = hv;
    __syncthreads();

    const int row = tid & 127, half = tid >> 7;
    const float4* wrow = (const float4*)(fc1_w + (size_t)row * H_DIM) + half * 128;
    float a0 = 0.f, a1 = 0.f;
    #pragma unroll 4
    for (int i = 0; i < 128; i += 2) {
        const float4 w0 = wrow[i],     h0 = hr4[half * 128 + i];
        const float4 w1 = wrow[i + 1], h1 = hr4[half * 128 + i + 1];
        a0 += w0.x * h0.x + w0.y * h0.y + w0.z * h0.z + w0.w * h0.w;
        a1 += w1.x * h1.x + w1.y * h1.y + w1.z * h1.z + w1.w * h1.w;
    }
    partial[tid] = a0 + a1;
    __syncthreads();
    if (tid < 128) {
        const float s = partial[tid] + partial[tid + 128] + fc1_b[tid];
        r1[tid] = fmaxf(s, 0.f);
    }
    __syncthreads();
    if (tid < 64) {
        float v = r1[tid] * fc2_w[tid] + r1[tid + 64] * fc2_w[tid + 64];
        #pragma unroll
        for (int off = 32; off > 0; off >>= 1) v += __shfl_xor(v, off, 64);
        if (tid == 0) out[0] = v + fc2_b[0];
    }
}

extern "C" void kernel_launch(void* const* d_in, const int* in_sizes, int n_in,
                              void* d_out, int out_size, void* d_ws, size_t ws_size,
                              hipStream_t stream) {
    (void)in_sizes; (void)n_in; (void)out_size; (void)ws_size;
    const float* xseq  = (const float*)d_in[0];
    const float* W_ih  = (const float*)d_in[1];
    const float* W_hh  = (const float*)d_in[2];
    const float* b_ih  = (const float*)d_in[3];
    const float* b_hh  = (const float*)d_in[4];
    const float* fc1_w = (const float*)d_in[5];
    const float* fc1_b = (const float*)d_in[6];
    const float* fc2_w = (const float*)d_in[7];
    const float* fc2_b = (const float*)d_in[8];
    unsigned* pairs = (unsigned*)d_ws;

    lstm_persistent<<<NBLK, NTHR, 0, stream>>>(xseq, W_ih, W_hh, b_ih, b_hh, pairs);
    fc_head<<<1, 256, 0, stream>>>(pairs, fc1_w, fc1_b, fc2_w, fc2_b, (float*)d_out);
}